// Round 1
// 268.369 us; speedup vs baseline: 1.0495x; 1.0495x over previous
//
#include <hip/hip_runtime.h>
#include <cstdint>

static constexpr int S = 1024;
static constexpr int T = 32;
static constexpr float L2E  = 1.4426950408889634f;  // log2(e)
static constexpr float LN2f = 0.6931471805599453f;  // ln(2)

typedef __attribute__((ext_vector_type(8)))  short  short8;
typedef __attribute__((ext_vector_type(16))) float  float16;

union Frag { unsigned u[4]; short8 s; };

__global__ void crf_zero(float* ws) {
  ws[0] = 0.0f; ws[1] = 0.0f; ((unsigned*)ws)[2] = 0u;
}

__device__ __forceinline__ float bcast_lane(float v, int k) {
  return __uint_as_float((unsigned)__builtin_amdgcn_readlane((int)__float_as_uint(v), k));
}

// single-instruction rounded pack: two f32 -> bf16x2 (lo = first arg).
// No builtin on gfx950 (learn_hip m240) -> inline asm per T12 recipe.
__device__ __forceinline__ unsigned cvtpk(float lo, float hi) {
  unsigned r;
  asm("v_cvt_pk_bf16_f32 %0, %1, %2" : "=v"(r) : "v"(lo), "v"(hi));
  return r;
}

// sigma: fixed row permutation mapping MFMA C-layout row slots onto B-operand
// row slots (swaps 4-blocks 1<->2 within each 16): slot k of the B operand is
// fed matrix row sigma(k). With A pre-permuted (A'[n][k] = P^T[n][sigma(k)])
// the product is exact and D's packed pairs ARE the next B - no lane swap.
__device__ __forceinline__ int sig(int k) {
  int g2 = (k >> 2) & 3;
  if (g2 == 1) g2 = 2; else if (g2 == 2) g2 = 1;
  return (k & ~12) | (g2 << 2);
}

// Block = one batch (512 thr = 8 waves). Active range (head, tail] split into
// 8 equal chunks; wave w folds its chunk into a 32x32 matrix via MFMA in the
// linear 2^x domain (M <- diag(g_j) P^T M). g staged in LDS as f32
// (4x broadcast ds_read_b128 per fold, no unpack); em loads for the next
// 16-step block are register-prefetched so their latency hides under folds.
// Wave 0 then scans the 8 chunk matrices.
__global__ __launch_bounds__(512, 8) void crf_main(
    const float* __restrict__ em, const int* __restrict__ tags,
    const int* __restrict__ mask, const float* __restrict__ startT,
    const float* __restrict__ trans, const float* __restrict__ endT,
    float* __restrict__ ws, float* __restrict__ out, int B)
{
  __shared__ __align__(16) float    s_g32[8 * 512];    // 16 KiB: f32 g staging (16 steps x 32 tags / wave)
  __shared__ __align__(16) unsigned s_mats[8 * 544];   // 17 KiB: bf16 chunk mats, rows pad 34
  __shared__ float s_trans[1024];                      // 4 KiB
  __shared__ short s_tags[1024];                       // 2 KiB
  __shared__ unsigned long long s_mb[17];
  __shared__ int   s_head, s_tail, s_cnt, s_K[8];
  __shared__ float s_num[8];

  const int tid = threadIdx.x;
  const int l   = tid & 63;
  const int wv  = tid >> 6;
  const int b   = blockIdx.x;
  const int n   = l & 31;        // MFMA column / tag index
  const int h   = l >> 5;        // lane half

  const float* emb   = em   + (size_t)b * S * T;
  const int*   maskb = mask + (size_t)b * S;
  const int*   tagsb = tags + (size_t)b * S;

  // ---- cooperative staging: tags, trans, mask ballots ----
  for (int i = tid; i < 1024; i += 512) {
    s_tags[i]  = (short)tagsb[i];
    s_trans[i] = trans[i];
  }
  {
    unsigned long long b0 = __ballot(maskb[wv * 128 + l] != 0);
    unsigned long long b1 = __ballot(maskb[wv * 128 + 64 + l] != 0);
    if (l == 0) { s_mb[2 * wv] = b0; s_mb[2 * wv + 1] = b1; }
    if (tid == 0) s_mb[16] = 0ull;
  }

  // ---- A' = sigma-permuted P^T as bf16 frags (lane: m=n, k-slot=8h+2p+par) ----
  Frag Alo, Ahi;
  #pragma unroll
  for (int p = 0; p < 4; ++p) {
    int k0 = 8 * h + 2 * p;
    Alo.u[p] = cvtpk(exp2f(trans[sig(k0 + 0)      * T + n] * L2E),
                     exp2f(trans[sig(k0 + 1)      * T + n] * L2E));
    Ahi.u[p] = cvtpk(exp2f(trans[sig(16 + k0 + 0) * T + n] * L2E),
                     exp2f(trans[sig(16 + k0 + 1) * T + n] * L2E));
  }
  __syncthreads();

  if (wv == 0) {
    int first = 0x7fffffff, last = -1, pc = 0;
    if (l < 16) {
      unsigned long long w = s_mb[l];
      if (w) {
        first = 64 * l + (int)__builtin_ctzll(w);
        last  = 64 * l + 63 - (int)__builtin_clzll(w);
        pc    = (int)__builtin_popcountll(w);
      }
    }
    #pragma unroll
    for (int d = 1; d < 64; d <<= 1) {
      first = min(first, __shfl_xor(first, d));
      last  = max(last,  __shfl_xor(last,  d));
      pc   += __shfl_xor(pc, d);
    }
    if (l == 0) { s_head = first; s_tail = last; s_cnt = pc; }
  }
  __syncthreads();
  const int cnt  = s_cnt;
  const int head = (cnt > 0) ? s_head : 0;
  const int tail = (cnt > 0) ? s_tail : 0;

  // ---- equal-split chunk for this wave ----
  const int span = tail - head;
  const int Lc   = (span + 7) >> 3;
  const int c0   = head + 1 + wv * Lc;
  const int c1   = min(c0 + Lc, tail + 1);

  float* sgw32 = s_g32 + wv * 512;
  Frag Blo, Bhi;                    // running M in sigma-storage, init = I
  #pragma unroll
  for (int p = 0; p < 4; ++p) {
    int k0 = 8 * h + 2 * p;
    Blo.u[p] = ((sig(k0) == n)          ? 0x3F80u : 0u) |
               ((sig(k0 + 1) == n)      ? 0x3F800000u : 0u);
    Bhi.u[p] = ((sig(16 + k0) == n)     ? 0x3F80u : 0u) |
               ((sig(16 + k0 + 1) == n) ? 0x3F800000u : 0u);
  }
  int   Kacc  = 0;
  float numer = 0.0f;

  // em prefetch regs: lane covers quarters i0=l (steps 0..7) and i1=l+64 (8..15)
  float4 v0, v1;
#define LOADEM(J0) do {                                                      \
    const int r0_ = min((J0) + (l >> 3),     S - 1);                         \
    const int r1_ = min((J0) + 8 + (l >> 3), S - 1);                         \
    v0 = ((const float4*)(emb + (size_t)r0_ * T))[l & 7];                    \
    v1 = ((const float4*)(emb + (size_t)r1_ * T))[l & 7];                    \
  } while (0)

#define STOREG() do {                                                        \
    float4 g0_, g1_;                                                         \
    g0_.x = exp2f(v0.x * L2E); g0_.y = exp2f(v0.y * L2E);                    \
    g0_.z = exp2f(v0.z * L2E); g0_.w = exp2f(v0.w * L2E);                    \
    g1_.x = exp2f(v1.x * L2E); g1_.y = exp2f(v1.y * L2E);                    \
    g1_.z = exp2f(v1.z * L2E); g1_.w = exp2f(v1.w * L2E);                    \
    ((float4*)sgw32)[l] = g0_; ((float4*)sgw32)[l + 64] = g1_;               \
  } while (0)

#define FOLD(JJ, RSC) do {                                                   \
    const float4* gw = (const float4*)(sgw32 + (JJ) * 32);                   \
    float4 wa = gw[h], wb = gw[h + 2], wc = gw[h + 4], wd = gw[h + 6];       \
    float16 D = {0,0,0,0,0,0,0,0,0,0,0,0,0,0,0,0};                           \
    D = __builtin_amdgcn_mfma_f32_32x32x16_bf16(Alo.s, Blo.s, D, 0, 0, 0);   \
    D = __builtin_amdgcn_mfma_f32_32x32x16_bf16(Ahi.s, Bhi.s, D, 0, 0, 0);   \
    D[0]  *= wa.x; D[1]  *= wa.y; D[2]  *= wa.z; D[3]  *= wa.w;              \
    D[4]  *= wb.x; D[5]  *= wb.y; D[6]  *= wb.z; D[7]  *= wb.w;              \
    D[8]  *= wc.x; D[9]  *= wc.y; D[10] *= wc.z; D[11] *= wc.w;              \
    D[12] *= wd.x; D[13] *= wd.y; D[14] *= wd.z; D[15] *= wd.w;              \
    if (RSC) {                                                               \
      float mx = fmaxf(fmaxf(fmaxf(D[0], D[1]), fmaxf(D[2], D[3])),          \
                       fmaxf(fmaxf(D[4], D[5]), fmaxf(D[6], D[7])));         \
      mx = fmaxf(mx, fmaxf(fmaxf(fmaxf(D[8], D[9]),  fmaxf(D[10], D[11])),   \
                           fmaxf(fmaxf(D[12], D[13]), fmaxf(D[14], D[15]))));\
      mx = fmaxf(mx, __shfl_xor(mx, 32));   /* full column-0 max */          \
      mx = __uint_as_float((unsigned)__builtin_amdgcn_readfirstlane(         \
               (int)__float_as_uint(mx)));                                   \
      int E = (int)((__float_as_uint(mx) >> 23) & 0xffu);                    \
      float sc = __uint_as_float((unsigned)(254 - E) << 23);                 \
      Kacc += E - 127;                                                       \
      _Pragma("unroll")                                                      \
      for (int q_ = 0; q_ < 16; ++q_) D[q_] *= sc;                           \
    }                                                                        \
    Blo.u[0] = cvtpk(D[0],  D[1]);  Blo.u[1] = cvtpk(D[2],  D[3]);           \
    Blo.u[2] = cvtpk(D[4],  D[5]);  Blo.u[3] = cvtpk(D[6],  D[7]);           \
    Bhi.u[0] = cvtpk(D[8],  D[9]);  Bhi.u[1] = cvtpk(D[10], D[11]);          \
    Bhi.u[2] = cvtpk(D[12], D[13]); Bhi.u[3] = cvtpk(D[14], D[15]);          \
  } while (0)

  if (c0 < c1) LOADEM(c0);

  for (int j0 = c0; j0 < c1; j0 += 16) {
    const int ns = min(16, c1 - j0);

    // convert prefetched em -> g = 2^(em*log2e) in LDS (f32)
    STOREG();
    // issue next block's loads now; latency hides under the folds below
    if (j0 + 16 < c1) LOADEM(j0 + 16);

    // 16-bit applied-mask at arbitrary offset j0 (funnel over ballot words)
    const int w = j0 >> 6, o = j0 & 63;
    unsigned long long bits = s_mb[w] >> o;
    if (o) bits |= s_mb[w + 1] << (64 - o);
    unsigned eff = (unsigned)(bits & 0xFFFFull) & (unsigned)((1u << ns) - 1u);

    // numerator: lanes 0..ns-1 take one step each (em recovered from f32 g)
    if (l < ns && ((eff >> l) & 1u)) {
      int j  = j0 + l;
      int tg = (int)s_tags[j], tp = (int)s_tags[j - 1];
      float gval = sgw32[l * 32 + tg];
      numer += s_trans[tp * T + tg] + log2f(gval) * LN2f;
    }

    if (eff == 0xFFFFu) {
      #pragma unroll
      for (int jj = 0; jj < 16; ++jj) FOLD(jj, ((jj & 7) == 7));
    } else {
      for (int jj = 0; jj < ns; ++jj)
        if ((eff >> jj) & 1u) FOLD(jj, true);
    }
  }
#undef FOLD
#undef STOREG
#undef LOADEM

  // ---- publish chunk matrix (packed bf16 row pairs, sigma-unscrambled) ----
  {
    unsigned* mw = s_mats + wv * 544;
    #pragma unroll
    for (int p = 0; p < 4; ++p) {
      mw[(sig(8 * h + 2 * p)      >> 1) * 34 + n] = Blo.u[p];
      mw[(sig(16 + 8 * h + 2 * p) >> 1) * 34 + n] = Bhi.u[p];
    }
  }
  #pragma unroll
  for (int d = 1; d < 64; d <<= 1) numer += __shfl_xor(numer, d);
  if (l == 0) { s_num[wv] = numer; s_K[wv] = Kacc; }
  __syncthreads();

  // ---- phase 2: wave 0 scans the 8 chunk matrices ----
  if (wv == 0) {
    const int t = n;
    const float em0 = emb[head * T + t];
    float sc0 = (startT[t] + em0) * L2E;
    float m0 = sc0;
    #pragma unroll
    for (int d = 1; d < 32; d <<= 1) m0 = fmaxf(m0, __shfl_xor(m0, d));
    float e = exp2f(sc0 - m0);
    float Mtot = m0;

    const unsigned sh = (t & 1) ? 0u : 16u;   // select row-half of packed word
    for (int c = 0; c < 8; ++c) {
      const unsigned* mw = s_mats + c * 544 + (t >> 1) * 34;
      float acc = 0.0f;
      #pragma unroll
      for (int q2 = 0; q2 < 16; ++q2) {
        uint2 w2 = *(const uint2*)(mw + 2 * q2);
        float vlo = __uint_as_float((w2.x << sh) & 0xFFFF0000u);
        float vhi = __uint_as_float((w2.y << sh) & 0xFFFF0000u);
        acc = fmaf(vlo, bcast_lane(e, 2 * q2), acc);
        acc = fmaf(vhi, bcast_lane(e, 2 * q2 + 1), acc);
      }
      e = acc;
      Mtot += (float)s_K[c];
      float mx = e;
      #pragma unroll
      for (int d = 1; d < 32; d <<= 1) mx = fmaxf(mx, __shfl_xor(mx, d));
      int E = (int)((__float_as_uint(mx) >> 23) & 0xffu);
      e *= __uint_as_float((unsigned)(254 - E) << 23);
      Mtot += (float)(E - 127);
    }

    float fv = e * exp2f(endT[t] * L2E);
    #pragma unroll
    for (int d = 1; d < 32; d <<= 1) fv += __shfl_xor(fv, d);
    float denom = (Mtot + log2f(fv)) * LN2f;

    if (l == 0) {
      if (cnt > 0) {
        float ntot = 0.0f;
        for (int wq = 0; wq < 8; ++wq) ntot += s_num[wq];
        int th = (int)s_tags[head], tt = (int)s_tags[tail];
        ntot += startT[th] + bcast_lane(em0, th) + endT[tt];
        atomicAdd(&ws[0], (denom - ntot) / ((float)cnt + 1e-6f));
        atomicAdd(&ws[1], 1.0f);
      }
      __threadfence();
      unsigned done = atomicAdd((unsigned*)ws + 2, 1u);
      if (done == (unsigned)(B - 1)) {
        __threadfence();
        out[0] = ws[0] / (ws[1] + 1e-6f);
      }
    }
  }
}

extern "C" void kernel_launch(void* const* d_in, const int* in_sizes, int n_in,
                              void* d_out, int out_size, void* d_ws, size_t ws_size,
                              hipStream_t stream) {
  const float* em     = (const float*)d_in[0];
  const int*   tags   = (const int*)d_in[1];
  const int*   mask   = (const int*)d_in[2];
  const float* startT = (const float*)d_in[3];
  const float* trans  = (const float*)d_in[4];
  const float* endT   = (const float*)d_in[5];
  float* out = (float*)d_out;
  float* ws  = (float*)d_ws;

  const int B = in_sizes[0] / (S * T);

  crf_zero<<<1, 1, 0, stream>>>(ws);
  crf_main<<<B, 512, 0, stream>>>(em, tags, mask, startT, trans, endT, ws, out, B);
}